// Round 13
// baseline (55.336 us; speedup 1.0000x reference)
//
#include <hip/hip_runtime.h>

typedef unsigned long long u64;
typedef unsigned int u32;

#define NBOX 8192
#define NW64 128    // u64 words per fallback suppression bitmap
#define NCLASS 80
#define MAXC 512    // clist capacity per class
#define NCMAX 256   // fast-path class size cap; nc>NCMAX flags exact fallback
#define CHKCAP 256
#define NS 32       // rank slices
#define SLICE 256   // NBOX / NS
#define NBLK 32     // i-range blocks
#define K1GRID (NS * NBLK + 1)  // 1024 rank blocks + 1 hazard block
#define K3GRID (NCLASS + 1)     // 80 class-NMS + 1 fallback

// ---- monotone float<->uint mapping (order-preserving for all floats) ----
__device__ __forceinline__ u32 f32_mono(float f) {
  u32 u = __float_as_uint(f);
  return (u & 0x80000000u) ? ~u : (u | 0x80000000u);
}
__device__ __forceinline__ float mono_f32(u32 u) {
  u32 b = (u & 0x80000000u) ? (u ^ 0x80000000u) : ~u;
  return __uint_as_float(b);
}
__device__ __forceinline__ u64 readlane64(u64 v, int l) {
  u32 lo = __builtin_amdgcn_readlane((u32)v, l);
  u32 hi = __builtin_amdgcn_readlane((u32)(v >> 32), l);
  return ((u64)hi << 32) | (u64)lo;
}
// reduce 32-entry u32 array of block maxima, in-register
__device__ __forceinline__ u32 reduce_bmax(const u32* __restrict__ bmax, int t) {
  u32 bm = bmax[t & 31];
#pragma unroll
  for (int off = 16; off > 0; off >>= 1) {
    u32 o = __shfl_xor(bm, off);
    bm = (bm > o) ? bm : o;
  }
  return bm;
}

// NOTES (measured lessons):
// r7/r8: in-kernel grid barriers dead on gfx950 (RMW convoy ~27us; fence L2
//   walk ~20us). Plain kernel nodes only.
// r10/r11: serial per-class IoU chain ~13us; mask-then-scan removes it.
// r12: node count is ~1us each (3->2 nodes saved 0.77us) — NOT the cost.
// r12 post-mortem: class blocks' self-gather + local-rank preamble ~30us.
//   This version precomputes rc/clist in K1/K2 so class blocks start cold
//   from a dense list (r5/r6 structure) + mask+scan (r11 fix).

// ---- K1: fused rank-by-enumeration (global cnt + class ccnt in ONE pass
// over a packed u64 LDS table (score_mono<<8)|cls) + box decode/bmax
// (slice 0) + hazard/hist block (sole flag writer, also stores ccount).
// rank = #{score_j > score_i} + #{score_j == score_i && j < i}.
__global__ __launch_bounds__(256) void rank_decode_kernel(
    const float* __restrict__ scores, const int* __restrict__ class_ids,
    const float4* __restrict__ deltas, const float2* __restrict__ locs,
    const int* __restrict__ stride_p, float4* __restrict__ boxes_out,
    u32* __restrict__ bmax, int* __restrict__ flag, int* __restrict__ ccount,
    int* __restrict__ rankp, int* __restrict__ rcp) {
  const int t = threadIdx.x;
  const int b = blockIdx.x;

  if (b == NS * NBLK) {
    // hazard block: recompute boxes + M locally (boxes_out concurrent).
    // (a) geometric hazard: adjacent-class offset boxes can only overlap if
    //     one hugs the top-right margin (x2,y2 > M-65; x1,y1 >= -64 by
    //     construction) and the other the bottom-left (x1,y1 < 1);
    //     conservative IoU > 0.4 vs reference 0.5.
    // (b) class-size overflow: any class with > NCMAX members.
    // Either -> flag=1 -> K3 fallback block recomputes everything exactly.
    __shared__ float4 bxA[CHKCAP], bxB[CHKCAP];
    __shared__ int clsA[CHKCAP], clsB[CHKCAP];
    __shared__ int hist[NCLASS];
    __shared__ int na, nb, hitf;
    __shared__ u32 mred[4];
    if (t == 0) { na = 0; nb = 0; hitf = 0; }
    if (t < NCLASS) hist[t] = 0;
    float s = (float)(*stride_p);
    u32 mymax = 0;
    for (int base = 0; base < NBOX; base += 256) {
      int i = base + t;
      float4 d = deltas[i];
      d.x = fmaxf(d.x, 0.f); d.y = fmaxf(d.y, 0.f);
      d.z = fmaxf(d.z, 0.f); d.w = fmaxf(d.w, 0.f);
      float2 c = locs[i];
      float x1 = c.x - s * d.x, y1 = c.y - s * d.y;
      float x2 = c.x + s * d.z, y2 = c.y + s * d.w;
      float m = fmaxf(fmaxf(x1, y1), fmaxf(x2, y2));
      u32 u = f32_mono(m);
      mymax = mymax > u ? mymax : u;
    }
#pragma unroll
    for (int off = 32; off > 0; off >>= 1) {
      u32 o = __shfl_xor(mymax, off);
      mymax = mymax > o ? mymax : o;
    }
    if ((t & 63) == 0) mred[t >> 6] = mymax;
    __syncthreads();  // mred ready; orders hist/na/nb init before atomics
    u32 g0 = mred[0] > mred[1] ? mred[0] : mred[1];
    u32 g1 = mred[2] > mred[3] ? mred[2] : mred[3];
    float M = mono_f32(g0 > g1 ? g0 : g1);  // max is order-exact
    float thrA = M - 65.0f;
    for (int base = 0; base < NBOX; base += 256) {
      int i = base + t;
      float4 d = deltas[i];
      d.x = fmaxf(d.x, 0.f); d.y = fmaxf(d.y, 0.f);
      d.z = fmaxf(d.z, 0.f); d.w = fmaxf(d.w, 0.f);
      float2 c = locs[i];
      float4 bb;
      bb.x = c.x - s * d.x; bb.y = c.y - s * d.y;
      bb.z = c.x + s * d.z; bb.w = c.y + s * d.w;
      int cls = class_ids[i];
      atomicAdd(&hist[cls], 1);
      if (bb.z > thrA && bb.w > thrA) {
        int p = atomicAdd(&na, 1);
        if (p < CHKCAP) { bxA[p] = bb; clsA[p] = cls; }
      }
      if (bb.x < 1.0f && bb.y < 1.0f) {
        int p = atomicAdd(&nb, 1);
        if (p < CHKCAP) { bxB[p] = bb; clsB[p] = cls; }
      }
    }
    __syncthreads();
    if (t < NCLASS) {
      ccount[t] = hist[t];  // plain store, finalized at K1 boundary
      if (hist[t] > NCMAX) atomicOr(&hitf, 1);
    }
    int NA = na < CHKCAP ? na : CHKCAP;
    int NB = nb < CHKCAP ? nb : CHKCAP;
    bool hit = (t == 0) && (na > CHKCAP || nb > CHKCAP);
    for (int pr = t; pr < NA * NB; pr += 256) {
      int a = pr / NB, b2 = pr % NB;
      if (clsB[b2] != clsA[a] + 1) continue;
      float offa = (float)clsA[a] * (M + 1.0f);
      float offb = (float)clsB[b2] * (M + 1.0f);
      float4 A = bxA[a], Bb = bxB[b2];
      A.x += offa; A.y += offa; A.z += offa; A.w += offa;
      Bb.x += offb; Bb.y += offb; Bb.z += offb; Bb.w += offb;
      float ltx = fmaxf(A.x, Bb.x), lty = fmaxf(A.y, Bb.y);
      float rbx = fminf(A.z, Bb.z), rby = fminf(A.w, Bb.w);
      float ww = fmaxf(rbx - ltx, 0.f), hh = fmaxf(rby - lty, 0.f);
      float inter = ww * hh;
      float aa = (A.z - A.x) * (A.w - A.y);
      float ab = (Bb.z - Bb.x) * (Bb.w - Bb.y);
      float iou = inter / (aa + ab - inter);
      if (iou > 0.4f) hit = true;
    }
    if (hit) atomicOr(&hitf, 1);
    __syncthreads();
    if (t == 0) *flag = hitf;  // sole writer; plain store clears stale value
    return;
  }

  // ---- rank blocks ----
  const int bi = b & 31;
  const int slice = b >> 5;
  const int i = bi * 256 + t;

  __shared__ u64 kt[SLICE];
  __shared__ u32 wmax[4];

  if (slice == 0) {  // decode boxes + per-block max
    float s = (float)(*stride_p);
    float4 d = deltas[i];
    d.x = fmaxf(d.x, 0.f); d.y = fmaxf(d.y, 0.f);
    d.z = fmaxf(d.z, 0.f); d.w = fmaxf(d.w, 0.f);
    float2 c = locs[i];
    float4 bb;
    bb.x = c.x - s * d.x;
    bb.y = c.y - s * d.y;
    bb.z = c.x + s * d.z;
    bb.w = c.y + s * d.w;
    boxes_out[i] = bb;
    float m = fmaxf(fmaxf(bb.x, bb.y), fmaxf(bb.z, bb.w));
    u32 u = f32_mono(m);
#pragma unroll
    for (int off = 32; off > 0; off >>= 1) {
      u32 o = __shfl_xor(u, off);
      u = (u > o) ? u : o;
    }
    if ((t & 63) == 0) wmax[t >> 6] = u;
  }

  {
    int j = slice * 256 + t;
    kt[t] = ((u64)f32_mono(scores[j]) << 8) | (u32)(class_ids[j] & 0xff);
  }
  __syncthreads();
  if (slice == 0 && t == 0) {
    u32 m0 = wmax[0] > wmax[1] ? wmax[0] : wmax[1];
    u32 m1 = wmax[2] > wmax[3] ? wmax[2] : wmax[3];
    bmax[bi] = m0 > m1 ? m0 : m1;
  }

  u64 wi = ((u64)f32_mono(scores[i]) << 8) | (u32)(class_ids[i] & 0xff);
  u64 si = wi >> 8;
  int tp = i - slice * 256;  // j<i <=> p<tp (tp<0: none; tp>=256: all)
  int cnt = 0, ccnt = 0;
#pragma unroll 8
  for (int p = 0; p < SLICE; ++p) {
    u64 wj = kt[p];  // wave-uniform LDS address -> broadcast
    u64 sj = wj >> 8;
    bool less = (sj > si) || (sj == si && p < tp);
    bool ceq = (((u32)(wj ^ wi)) & 0xffu) == 0u;
    cnt += less ? 1 : 0;
    ccnt += (less && ceq) ? 1 : 0;
  }
  rankp[slice * NBOX + i] = cnt;
  rcp[slice * NBOX + i] = ccnt;
}

// ---- K2: scatter by rank — sorted keys, offset boxes, order output, and
// dense per-class sorted lists clist[cls][rc] = (idx<<16)|sorted_pos.
__global__ __launch_bounds__(256) void scatter_kernel(
    const float* __restrict__ scores, const int* __restrict__ class_ids,
    const float4* __restrict__ boxes, const u32* __restrict__ bmax,
    const int* __restrict__ rankp, const int* __restrict__ rcp,
    u64* __restrict__ keys, float4* __restrict__ bnms,
    u32* __restrict__ clist, float* __restrict__ order_out) {
  const int t = threadIdx.x;
  const int i = blockIdx.x * 256 + t;
  int r = 0, rc = 0;
#pragma unroll
  for (int s2 = 0; s2 < NS; ++s2) {  // coalesced within each slice row
    r += rankp[s2 * NBOX + i];
    rc += rcp[s2 * NBOX + i];
  }
  float maxc = mono_f32(reduce_bmax(bmax, t));
  u32 mi = f32_mono(scores[i]);
  keys[r] = ((u64)(~mi) << 32) | (u32)i;  // clean key for fallback
  int cls = class_ids[i];
  float off = (float)cls * (maxc + 1.0f);
  float4 bb = boxes[i];
  bb.x += off; bb.y += off; bb.z += off; bb.w += off;
  bnms[r] = bb;
  order_out[r] = (float)i;
  if (rc < MAXC) clist[cls * MAXC + rc] = ((u32)i << 16) | (u32)r;
}

// ---- K3: per-class mask+scan NMS (blocks 0..79; zero gather, zero local
// rank — clist/ccount precomputed) + exact fallback (block 80, flag != 0
// only). flag finalized in K1, clist/keys/bnms finalized in K2 — keep_out
// written by class blocks XOR fallback, no race.
__global__ __launch_bounds__(256) void nms_kernel(
    const u32* __restrict__ clist, const int* __restrict__ ccount,
    const float4* __restrict__ bnms, const u64* __restrict__ keys,
    float* __restrict__ keep_out, const int* __restrict__ flag) {
  const int t = threadIdx.x;
  const int bid = blockIdx.x;

  if (bid < NCLASS) {
    if (*flag != 0) return;  // fallback covers everything (uniform branch)
    const int c = bid;
    int nc = ccount[c];
    if (nc > NCMAX) return;  // defensive; K1 histogram already set flag
    __shared__ u32 elist[NCMAX];
    __shared__ float4 bx[NCMAX];
    __shared__ u64 smask[NCMAX][4];
    for (int k = t; k < nc; k += 256) {
      u32 e = clist[c * MAXC + k];  // coalesced dense list
      elist[k] = e;
      bx[k] = bnms[e & 0xffffu];    // already class-offset
    }
    __syncthreads();

    // parallel mask build: row i by wave (i&3); one ballot per 64-j word;
    // no loop-carried dependency.
    {
      const int wv = t >> 6;
      const int lane = t & 63;
      const int nw = (nc + 63) >> 6;
      for (int i = wv; i < nc; i += 4) {
        float4 bi = bx[i];  // uniform LDS address -> broadcast
        float area_i = (bi.z - bi.x) * (bi.w - bi.y);
        for (int w = 0; w < nw; ++w) {
          int j2 = w * 64 + lane;
          float4 bj = bx[j2 < NCMAX ? j2 : 0];
          float ltx = fmaxf(bi.x, bj.x), lty = fmaxf(bi.y, bj.y);
          float rbx = fminf(bi.z, bj.z), rby = fminf(bi.w, bj.w);
          float ww = fmaxf(rbx - ltx, 0.f), hh = fmaxf(rby - lty, 0.f);
          float inter = ww * hh;
          float area_j = (bj.z - bj.x) * (bj.w - bj.y);
          float iou = inter / (area_i + area_j - inter);
          bool p = (iou > 0.5f) && (j2 > i) && (j2 < nc);
          u64 mm = __ballot(p);
          if (lane == 0) smask[i][w] = mm;
        }
      }
    }
    __syncthreads();
    if (t >= 64) return;

    // wave 0: bitmask-only greedy scan (no IoU in the serial chain).
    u64 ma[4], mb[4], mc[4], md[4];
#pragma unroll
    for (int w = 0; w < 4; ++w) {
      ma[w] = smask[t][w];
      mb[w] = smask[64 + t][w];
      mc[w] = smask[128 + t][w];
      md[w] = smask[192 + t][w];
    }
    u64 R0 = 0, R1 = 0, R2 = 0, R3 = 0;
    u64 K0 = 0, K1 = 0, K2 = 0, K3 = 0;

#define SCAND(D, MD, RD, KD)                                                   \
  {                                                                            \
    int lim = nc - (D) * 64;                                                   \
    if (lim > 0) {                                                             \
      if (lim > 64) lim = 64;                                                  \
      for (int ii = 0; ii < lim; ++ii) {                                       \
        u64 kb = ((RD >> ii) & 1ull) ^ 1ull;                                   \
        KD |= kb << ii;                                                        \
        u64 sm2 = 0ull - kb;                                                   \
        R0 |= readlane64(MD[0], ii) & sm2;                                     \
        R1 |= readlane64(MD[1], ii) & sm2;                                     \
        R2 |= readlane64(MD[2], ii) & sm2;                                     \
        R3 |= readlane64(MD[3], ii) & sm2;                                     \
      }                                                                        \
    }                                                                          \
  }
    SCAND(0, ma, R0, K0)
    SCAND(1, mb, R1, K1)
    SCAND(2, mc, R2, K2)
    SCAND(3, md, R3, K3)
#undef SCAND

    u64 kk[4] = {K0, K1, K2, K3};
#pragma unroll
    for (int d = 0; d < 4; ++d) {
      int j = d * 64 + t;
      if (j < nc) keep_out[elist[j] >> 16] = ((kk[d] >> t) & 1ull) ? 1.0f : 0.0f;
    }
    return;
  }

  // ---- block 80: exact single-block fallback (flag != 0 only) ----
  if (*flag == 0) return;
  __shared__ u64 remv[NW64];
  for (int k = t; k < NW64; k += 256) remv[k] = 0;
  __syncthreads();
  if (t < 64) {
    int lane = t;
    for (int ii = 0; ii < NBOX; ++ii) {
      if ((remv[ii >> 6] >> (ii & 63)) & 1ull) continue;
      float4 bi = bnms[ii];
      float area_i = (bi.z - bi.x) * (bi.w - bi.y);
      for (int jb = ii + 1; jb < NBOX; jb += 64) {
        int j = jb + lane;
        bool p = false;
        if (j < NBOX) {
          float4 bj = bnms[j];
          float ltx = fmaxf(bi.x, bj.x), lty = fmaxf(bi.y, bj.y);
          float rbx = fminf(bi.z, bj.z), rby = fminf(bi.w, bj.w);
          float ww = fmaxf(rbx - ltx, 0.f), hh = fmaxf(rby - lty, 0.f);
          float inter = ww * hh;
          float area_j = (bj.z - bj.x) * (bj.w - bj.y);
          float iou = inter / (area_i + area_j - inter);
          p = iou > 0.5f;
        }
        u64 m = __ballot(p);
        if (lane == 0 && m) {
          int w0 = jb >> 6, sh = jb & 63;
          remv[w0] |= (m << sh);
          if (sh && (w0 + 1) < NW64) remv[w0 + 1] |= (m >> (64 - sh));
        }
      }
    }
  }
  __syncthreads();
  for (int k = t; k < NBOX; k += 256)
    keep_out[(u32)keys[k]] = ((remv[k >> 6] >> (k & 63)) & 1ull) ? 0.0f : 1.0f;
}

extern "C" void kernel_launch(void* const* d_in, const int* in_sizes, int n_in,
                              void* d_out, int out_size, void* d_ws, size_t ws_size,
                              hipStream_t stream) {
  const float* deltas = (const float*)d_in[0];
  const float* locs = (const float*)d_in[1];
  const float* scores = (const float*)d_in[2];
  const int* class_ids = (const int*)d_in[3];
  const int* stride_p = (const int*)d_in[4];

  float* boxes_out = (float*)d_out;                     // n*4 floats
  float* keep_out = (float*)d_out + (size_t)NBOX * 4;   // n floats (0/1)
  float* order_out = (float*)d_out + (size_t)NBOX * 5;  // n floats (indices)

  // workspace layout (all init in-kernel; no memset nodes)
  u32* bmax = (u32*)((char*)d_ws + 64);           // 32*4 B, plain-stored
  int* flag = (int*)((char*)d_ws + 256);          // stored by K1 hazard block
  int* ccount = (int*)((char*)d_ws + 512);        // 80*4 B, stored by K1
  u64* keys = (u64*)((char*)d_ws + 4096);         // 64 KiB
  float4* bnms = (float4*)((char*)d_ws + 4096 + 65536);  // 128 KiB
  char* base2 = (char*)d_ws + 4096 + 65536 + 131072;
  int* rankp = (int*)base2;                        // 1 MiB
  int* rcp = (int*)(base2 + 1024 * 1024);          // 1 MiB
  u32* clist = (u32*)(base2 + 2048 * 1024);        // 160 KiB

  rank_decode_kernel<<<K1GRID, 256, 0, stream>>>(
      scores, class_ids, (const float4*)deltas, (const float2*)locs, stride_p,
      (float4*)boxes_out, bmax, flag, ccount, rankp, rcp);

  scatter_kernel<<<NBLK, 256, 0, stream>>>(
      scores, class_ids, (const float4*)boxes_out, bmax, rankp, rcp, keys,
      bnms, clist, order_out);

  nms_kernel<<<K3GRID, 256, 0, stream>>>(clist, ccount, bnms, keys, keep_out,
                                         flag);
}

// Round 14
// 44.715 us; speedup vs baseline: 1.2375x; 1.2375x over previous
//
#include <hip/hip_runtime.h>

typedef unsigned long long u64;
typedef unsigned int u32;

#define NBOX 8192
#define NW64 128    // u64 words per fallback suppression bitmap
#define NCLASS 80
#define NCMAX 256   // fast-path class size cap; overflow flags exact fallback
#define CHKCAP 256
#define NS 32       // rank slices
#define SLICE 256   // NBOX / NS
#define NBLK 32     // i-range blocks
#define RANKB (NS * NBLK)          // 1024
#define K1GRID (RANKB + 1 + NCLASS)  // rank + hazard + class-NMS
#define K2GRID (NBLK + 1)            // scatter + fallback

// ---- monotone float<->uint mapping (order-preserving for all floats) ----
__device__ __forceinline__ u32 f32_mono(float f) {
  u32 u = __float_as_uint(f);
  return (u & 0x80000000u) ? ~u : (u | 0x80000000u);
}
__device__ __forceinline__ float mono_f32(u32 u) {
  u32 b = (u & 0x80000000u) ? (u ^ 0x80000000u) : ~u;
  return __uint_as_float(b);
}
__device__ __forceinline__ u64 readlane64(u64 v, int l) {
  u32 lo = __builtin_amdgcn_readlane((u32)v, l);
  u32 hi = __builtin_amdgcn_readlane((u32)(v >> 32), l);
  return ((u64)hi << 32) | (u64)lo;
}
__device__ __forceinline__ u32 reduce_bmax(const u32* __restrict__ bmax, int t) {
  u32 bm = bmax[t & 31];
#pragma unroll
  for (int off = 16; off > 0; off >>= 1) {
    u32 o = __shfl_xor(bm, off);
    bm = (bm > o) ? bm : o;
  }
  return bm;
}

// NOTES (measured lessons):
// r7/r8: in-kernel grid barriers dead on gfx950 (~20-27us each). Plain nodes.
// r11: mask-then-scan beats serial-IoU chain (+13us).
// r12: node count ~1us each — not the cost.
// r13: precomputing clist did NOT help -> class-block preamble is cheap; the
//   cost was SERIALIZING the class kernel after the rank kernel. This round:
//   class-NMS blocks are self-contained (own M, own gather) and run IN THE
//   SAME LAUNCH as the rank blocks — the only true deps (scatter, fallback)
//   move to a tiny K2.

// ---- K1: [b<1024] u32 score-rank partials + box decode/bmax (slice 0)
//          [b==1024] hazard + class-size histogram -> flag (sole writer)
//          [b>1024] self-contained per-class NMS -> keep_out
__global__ __launch_bounds__(256) void fused_kernel(
    const float* __restrict__ scores, const int* __restrict__ class_ids,
    const float4* __restrict__ deltas, const float2* __restrict__ locs,
    const int* __restrict__ stride_p, float4* __restrict__ boxes_out,
    float* __restrict__ keep_out, u32* __restrict__ bmax,
    int* __restrict__ flag, int* __restrict__ rankp) {
  const int t = threadIdx.x;
  const int b = blockIdx.x;

  if (b < RANKB) {
    // ---- rank blocks: rank = #{s_j > s_i} + #{s_j == s_i && j < i} ----
    const int bi = b & 31;
    const int slice = b >> 5;
    const int i = bi * 256 + t;

    __shared__ u32 st[SLICE];
    __shared__ u32 wmax[4];

    if (slice == 0) {  // decode boxes + per-block max
      float s = (float)(*stride_p);
      float4 d = deltas[i];
      d.x = fmaxf(d.x, 0.f); d.y = fmaxf(d.y, 0.f);
      d.z = fmaxf(d.z, 0.f); d.w = fmaxf(d.w, 0.f);
      float2 c = locs[i];
      float4 bb;
      bb.x = c.x - s * d.x;
      bb.y = c.y - s * d.y;
      bb.z = c.x + s * d.z;
      bb.w = c.y + s * d.w;
      boxes_out[i] = bb;
      float m = fmaxf(fmaxf(bb.x, bb.y), fmaxf(bb.z, bb.w));
      u32 u = f32_mono(m);
#pragma unroll
      for (int off = 32; off > 0; off >>= 1) {
        u32 o = __shfl_xor(u, off);
        u = (u > o) ? u : o;
      }
      if ((t & 63) == 0) wmax[t >> 6] = u;
    }

    st[t] = f32_mono(scores[slice * 256 + t]);
    __syncthreads();
    if (slice == 0 && t == 0) {
      u32 m0 = wmax[0] > wmax[1] ? wmax[0] : wmax[1];
      u32 m1 = wmax[2] > wmax[3] ? wmax[2] : wmax[3];
      bmax[bi] = m0 > m1 ? m0 : m1;  // plain store (for K2 fallback)
    }

    u32 mi = f32_mono(scores[i]);
    int tp = i - slice * 256;  // j<i <=> p<tp
    int cnt = 0;
#pragma unroll 8
    for (int p = 0; p < SLICE; ++p) {
      u32 mj = st[p];  // uniform LDS address -> broadcast
      bool less = (mj > mi) || (mj == mi && p < tp);
      cnt += less ? 1 : 0;
    }
    rankp[slice * NBOX + i] = cnt;
    return;
  }

  if (b == RANKB) {
    // ---- hazard block (sole flag writer; recomputes boxes + M locally).
    // (a) geometric: adjacent-class offset boxes can only overlap if one
    //     hugs the top-right margin (x2,y2 > M-65; x1,y1 >= -64 by
    //     construction) and the other the bottom-left (x1,y1 < 1);
    //     conservative IoU > 0.4 vs reference 0.5.
    // (b) overflow: any class with > NCMAX members.
    __shared__ float4 bxA[CHKCAP], bxB[CHKCAP];
    __shared__ int clsA[CHKCAP], clsB[CHKCAP];
    __shared__ int hist[NCLASS];
    __shared__ int na, nb, hitf;
    __shared__ u32 mred[4];
    if (t == 0) { na = 0; nb = 0; hitf = 0; }
    if (t < NCLASS) hist[t] = 0;
    float s = (float)(*stride_p);
    u32 mymax = 0;
    for (int base = 0; base < NBOX; base += 256) {
      int i = base + t;
      float4 d = deltas[i];
      d.x = fmaxf(d.x, 0.f); d.y = fmaxf(d.y, 0.f);
      d.z = fmaxf(d.z, 0.f); d.w = fmaxf(d.w, 0.f);
      float2 c = locs[i];
      float x1 = c.x - s * d.x, y1 = c.y - s * d.y;
      float x2 = c.x + s * d.z, y2 = c.y + s * d.w;
      float m = fmaxf(fmaxf(x1, y1), fmaxf(x2, y2));
      u32 u = f32_mono(m);
      mymax = mymax > u ? mymax : u;
    }
#pragma unroll
    for (int off = 32; off > 0; off >>= 1) {
      u32 o = __shfl_xor(mymax, off);
      mymax = mymax > o ? mymax : o;
    }
    if ((t & 63) == 0) mred[t >> 6] = mymax;
    __syncthreads();  // mred ready; orders hist/na/nb init before atomics
    u32 g0 = mred[0] > mred[1] ? mred[0] : mred[1];
    u32 g1 = mred[2] > mred[3] ? mred[2] : mred[3];
    float M = mono_f32(g0 > g1 ? g0 : g1);
    float thrA = M - 65.0f;
    for (int base = 0; base < NBOX; base += 256) {
      int i = base + t;
      float4 d = deltas[i];
      d.x = fmaxf(d.x, 0.f); d.y = fmaxf(d.y, 0.f);
      d.z = fmaxf(d.z, 0.f); d.w = fmaxf(d.w, 0.f);
      float2 c = locs[i];
      float4 bb;
      bb.x = c.x - s * d.x; bb.y = c.y - s * d.y;
      bb.z = c.x + s * d.z; bb.w = c.y + s * d.w;
      int cls = class_ids[i];
      atomicAdd(&hist[cls], 1);
      if (bb.z > thrA && bb.w > thrA) {
        int p = atomicAdd(&na, 1);
        if (p < CHKCAP) { bxA[p] = bb; clsA[p] = cls; }
      }
      if (bb.x < 1.0f && bb.y < 1.0f) {
        int p = atomicAdd(&nb, 1);
        if (p < CHKCAP) { bxB[p] = bb; clsB[p] = cls; }
      }
    }
    __syncthreads();
    if (t < NCLASS && hist[t] > NCMAX) atomicOr(&hitf, 1);
    int NA = na < CHKCAP ? na : CHKCAP;
    int NB = nb < CHKCAP ? nb : CHKCAP;
    bool hit = (t == 0) && (na > CHKCAP || nb > CHKCAP);
    for (int pr = t; pr < NA * NB; pr += 256) {
      int a = pr / NB, b2 = pr % NB;
      if (clsB[b2] != clsA[a] + 1) continue;
      float offa = (float)clsA[a] * (M + 1.0f);
      float offb = (float)clsB[b2] * (M + 1.0f);
      float4 A = bxA[a], Bb = bxB[b2];
      A.x += offa; A.y += offa; A.z += offa; A.w += offa;
      Bb.x += offb; Bb.y += offb; Bb.z += offb; Bb.w += offb;
      float ltx = fmaxf(A.x, Bb.x), lty = fmaxf(A.y, Bb.y);
      float rbx = fminf(A.z, Bb.z), rby = fminf(A.w, Bb.w);
      float ww = fmaxf(rbx - ltx, 0.f), hh = fmaxf(rby - lty, 0.f);
      float inter = ww * hh;
      float aa = (A.z - A.x) * (A.w - A.y);
      float ab = (Bb.z - Bb.x) * (Bb.w - Bb.y);
      float iou = inter / (aa + ab - inter);
      if (iou > 0.4f) hit = true;
    }
    if (hit) atomicOr(&hitf, 1);
    __syncthreads();
    if (t == 0) *flag = hitf;  // plain store; clears stale value per replay
    return;
  }

  // ---- class blocks: fully self-contained (no dep on rank/hazard) ----
  const int c = b - (RANKB + 1);
  __shared__ u64 ck[NCMAX];
  __shared__ u32 slist[NCMAX];
  __shared__ float4 bx[NCMAX];
  __shared__ u64 smask[NCMAX][4];
  __shared__ u32 cmred[4];
  __shared__ int cnt_s;
  if (t == 0) cnt_s = 0;

  // 1) local M (exact fmax reduction — order-independent)
  float s = (float)(*stride_p);
  u32 mymax = 0;
  for (int base = 0; base < NBOX; base += 256) {
    int i = base + t;
    float4 d = deltas[i];
    d.x = fmaxf(d.x, 0.f); d.y = fmaxf(d.y, 0.f);
    d.z = fmaxf(d.z, 0.f); d.w = fmaxf(d.w, 0.f);
    float2 cc = locs[i];
    float x1 = cc.x - s * d.x, y1 = cc.y - s * d.y;
    float x2 = cc.x + s * d.z, y2 = cc.y + s * d.w;
    float m = fmaxf(fmaxf(x1, y1), fmaxf(x2, y2));
    u32 u = f32_mono(m);
    mymax = mymax > u ? mymax : u;
  }
#pragma unroll
  for (int off = 32; off > 0; off >>= 1) {
    u32 o = __shfl_xor(mymax, off);
    mymax = mymax > o ? mymax : o;
  }
  if ((t & 63) == 0) cmred[t >> 6] = mymax;
  __syncthreads();  // publishes cmred and cnt_s=0
  u32 g0 = cmred[0] > cmred[1] ? cmred[0] : cmred[1];
  u32 g1 = cmred[2] > cmred[3] ? cmred[2] : cmred[3];
  float M = mono_f32(g0 > g1 ? g0 : g1);
  float off = (float)c * (M + 1.0f);

  // 2) gather my class's items (prefetched one stride ahead)
  {
    int nxtc = class_ids[t];
    float nxts = scores[t];
    for (int base = 0; base < NBOX; base += 256) {
      int cur = nxtc;
      float cs = nxts;
      if (base + 256 < NBOX) {
        nxtc = class_ids[base + 256 + t];
        nxts = scores[base + 256 + t];
      }
      if (cur == c) {
        int p = atomicAdd(&cnt_s, 1);
        if (p < NCMAX) ck[p] = ((u64)(~f32_mono(cs)) << 32) | (u32)(base + t);
      }
    }
  }
  __syncthreads();
  int nc = cnt_s;
  if (nc > NCMAX) return;  // hazard block's histogram flags -> K2 fallback

  // 3) local stable rank: ascending (~mono(score), idx) == (score desc, idx)
  if (t < nc) {
    u64 kme = ck[t];
    int r2 = 0;
    for (int p = 0; p < nc; ++p) r2 += (ck[p] < kme) ? 1 : 0;
    slist[r2] = (u32)kme;  // low 32 = original idx
  }
  __syncthreads();

  // 4) decode + offset boxes for my items (same float-op order as reference)
  for (int k = t; k < nc; k += 256) {
    u32 idx = slist[k];
    float4 d = deltas[idx];
    d.x = fmaxf(d.x, 0.f); d.y = fmaxf(d.y, 0.f);
    d.z = fmaxf(d.z, 0.f); d.w = fmaxf(d.w, 0.f);
    float2 cc = locs[idx];
    float4 bb;
    bb.x = (cc.x - s * d.x) + off;
    bb.y = (cc.y - s * d.y) + off;
    bb.z = (cc.x + s * d.z) + off;
    bb.w = (cc.y + s * d.w) + off;
    bx[k] = bb;
  }
  __syncthreads();

  // 5) parallel mask build: row i by wave (i&3); one ballot per 64-j word
  {
    const int wv = t >> 6;
    const int lane = t & 63;
    const int nw = (nc + 63) >> 6;
    for (int i = wv; i < nc; i += 4) {
      float4 bi = bx[i];  // uniform LDS address -> broadcast
      float area_i = (bi.z - bi.x) * (bi.w - bi.y);
      for (int w = 0; w < nw; ++w) {
        int j2 = w * 64 + lane;
        float4 bj = bx[j2 < NCMAX ? j2 : 0];
        float ltx = fmaxf(bi.x, bj.x), lty = fmaxf(bi.y, bj.y);
        float rbx = fminf(bi.z, bj.z), rby = fminf(bi.w, bj.w);
        float ww = fmaxf(rbx - ltx, 0.f), hh = fmaxf(rby - lty, 0.f);
        float inter = ww * hh;
        float area_j = (bj.z - bj.x) * (bj.w - bj.y);
        float iou = inter / (area_i + area_j - inter);
        bool p = (iou > 0.5f) && (j2 > i) && (j2 < nc);
        u64 mm = __ballot(p);
        if (lane == 0) smask[i][w] = mm;
      }
    }
  }
  __syncthreads();
  if (t >= 64) return;

  // 6) wave 0: bitmask-only greedy scan (no IoU in the serial chain)
  u64 ma[4], mb[4], mc[4], md[4];
#pragma unroll
  for (int w = 0; w < 4; ++w) {
    ma[w] = smask[t][w];
    mb[w] = smask[64 + t][w];
    mc[w] = smask[128 + t][w];
    md[w] = smask[192 + t][w];
  }
  u64 R0 = 0, R1 = 0, R2 = 0, R3 = 0;
  u64 K0 = 0, K1 = 0, K2 = 0, K3 = 0;

#define SCAND(D, MD, RD, KD)                                                   \
  {                                                                            \
    int lim = nc - (D) * 64;                                                   \
    if (lim > 0) {                                                             \
      if (lim > 64) lim = 64;                                                  \
      for (int ii = 0; ii < lim; ++ii) {                                       \
        u64 kb = ((RD >> ii) & 1ull) ^ 1ull;                                   \
        KD |= kb << ii;                                                        \
        u64 sm2 = 0ull - kb;                                                   \
        R0 |= readlane64(MD[0], ii) & sm2;                                     \
        R1 |= readlane64(MD[1], ii) & sm2;                                     \
        R2 |= readlane64(MD[2], ii) & sm2;                                     \
        R3 |= readlane64(MD[3], ii) & sm2;                                     \
      }                                                                        \
    }                                                                          \
  }
  SCAND(0, ma, R0, K0)
  SCAND(1, mb, R1, K1)
  SCAND(2, mc, R2, K2)
  SCAND(3, md, R3, K3)
#undef SCAND

  u64 kk[4] = {K0, K1, K2, K3};
#pragma unroll
  for (int d = 0; d < 4; ++d) {
    int j = d * 64 + t;
    if (j < nc) keep_out[slist[j]] = ((kk[d] >> t) & 1ull) ? 1.0f : 0.0f;
  }
}

// ---- K2: scatter (blocks 0..31: order_out only) + exact fallback
// (block 32, flag != 0 only; self-contained — rebuilds perm from rankp and
// boxes from boxes_out, never reads anything a peer block writes).
__global__ __launch_bounds__(256) void scatter_fallback_kernel(
    const int* __restrict__ class_ids, const float4* __restrict__ boxes,
    const u32* __restrict__ bmax, const int* __restrict__ rankp,
    float* __restrict__ order_out, float* __restrict__ keep_out,
    const int* __restrict__ flag) {
  const int t = threadIdx.x;
  const int bid = blockIdx.x;

  if (bid < NBLK) {  // ---- scatter: order output ----
    int i = bid * 256 + t;
    int r = 0;
#pragma unroll
    for (int s2 = 0; s2 < NS; ++s2) r += rankp[s2 * NBOX + i];
    order_out[r] = (float)i;
    return;
  }

  // ---- block 32: exact fallback ----
  if (*flag == 0) return;
  __shared__ u32 perm[NBOX];  // 32 KiB
  __shared__ u64 remv[NW64];
  for (int k = t; k < NW64; k += 256) remv[k] = 0;
  for (int i = t; i < NBOX; i += 256) {
    int r = 0;
#pragma unroll
    for (int s2 = 0; s2 < NS; ++s2) r += rankp[s2 * NBOX + i];
    perm[r] = (u32)i;
  }
  __syncthreads();
  float maxc = mono_f32(reduce_bmax(bmax, t));
  if (t < 64) {
    int lane = t;
    for (int ii = 0; ii < NBOX; ++ii) {
      if ((remv[ii >> 6] >> (ii & 63)) & 1ull) continue;
      u32 pi = perm[ii];
      float offi = (float)class_ids[pi] * (maxc + 1.0f);
      float4 bi = boxes[pi];
      bi.x += offi; bi.y += offi; bi.z += offi; bi.w += offi;
      float area_i = (bi.z - bi.x) * (bi.w - bi.y);
      for (int jb = ii + 1; jb < NBOX; jb += 64) {
        int j = jb + lane;
        bool p = false;
        if (j < NBOX) {
          u32 pj = perm[j];
          float offj = (float)class_ids[pj] * (maxc + 1.0f);
          float4 bj = boxes[pj];
          bj.x += offj; bj.y += offj; bj.z += offj; bj.w += offj;
          float ltx = fmaxf(bi.x, bj.x), lty = fmaxf(bi.y, bj.y);
          float rbx = fminf(bi.z, bj.z), rby = fminf(bi.w, bj.w);
          float ww = fmaxf(rbx - ltx, 0.f), hh = fmaxf(rby - lty, 0.f);
          float inter = ww * hh;
          float area_j = (bj.z - bj.x) * (bj.w - bj.y);
          float iou = inter / (area_i + area_j - inter);
          p = iou > 0.5f;
        }
        u64 m = __ballot(p);
        if (lane == 0 && m) {
          int w0 = jb >> 6, sh = jb & 63;
          remv[w0] |= (m << sh);
          if (sh && (w0 + 1) < NW64) remv[w0 + 1] |= (m >> (64 - sh));
        }
      }
    }
  }
  __syncthreads();
  for (int k = t; k < NBOX; k += 256)
    keep_out[perm[k]] = ((remv[k >> 6] >> (k & 63)) & 1ull) ? 0.0f : 1.0f;
}

extern "C" void kernel_launch(void* const* d_in, const int* in_sizes, int n_in,
                              void* d_out, int out_size, void* d_ws, size_t ws_size,
                              hipStream_t stream) {
  const float* deltas = (const float*)d_in[0];
  const float* locs = (const float*)d_in[1];
  const float* scores = (const float*)d_in[2];
  const int* class_ids = (const int*)d_in[3];
  const int* stride_p = (const int*)d_in[4];

  float* boxes_out = (float*)d_out;                     // n*4 floats
  float* keep_out = (float*)d_out + (size_t)NBOX * 4;   // n floats (0/1)
  float* order_out = (float*)d_out + (size_t)NBOX * 5;  // n floats (indices)

  // workspace layout (all init in-kernel; no memset nodes)
  u32* bmax = (u32*)((char*)d_ws + 64);    // 32*4 B, plain-stored
  int* flag = (int*)((char*)d_ws + 256);   // stored by K1 hazard block
  int* rankp = (int*)((char*)d_ws + 4096); // NS*8192*4 = 1 MiB

  fused_kernel<<<K1GRID, 256, 0, stream>>>(
      scores, class_ids, (const float4*)deltas, (const float2*)locs, stride_p,
      (float4*)boxes_out, keep_out, bmax, flag, rankp);

  scatter_fallback_kernel<<<K2GRID, 256, 0, stream>>>(
      class_ids, (const float4*)boxes_out, bmax, rankp, order_out, keep_out,
      flag);
}